// Round 1
// baseline (645.754 us; speedup 1.0000x reference)
//
#include <hip/hip_runtime.h>

#define N_NODES 100000
#define N_EDGES 1600000
#define IN_DIM  256
#define OUT_DIM 128
#define BATCH_N 8192
#define SLOPE   0.1f
#define EPS_V   1e-8f

// ---------------- init: slot=-1, num=0, denom=0, counter=0 ----------------
__global__ __launch_bounds__(256) void init_kernel(int* __restrict__ slot, float* __restrict__ num,
                                                   float* __restrict__ denom, int* __restrict__ counter) {
  int i0 = blockIdx.x * blockDim.x + threadIdx.x;
  int stride = gridDim.x * blockDim.x;
  const int TOT = BATCH_N * OUT_DIM;   // 1,048,576 > N_NODES
  for (int i = i0; i < TOT; i += stride) {
    num[i] = 0.f;
    if (i < N_NODES) slot[i] = -1;
    if (i < BATCH_N) denom[i] = 0.f;
    if (i == 0) counter[0] = 0;
  }
}

// ---------------- slots: node -> slot map (races between duplicate nodes are
// benign: one aligned-32b writer wins, and all later readers see the same winner)
__global__ __launch_bounds__(256) void slots_kernel(const int* __restrict__ batch_idx, int* __restrict__ slot) {
  int i = blockIdx.x * blockDim.x + threadIdx.x;
  if (i < BATCH_N) slot[batch_idx[i]] = i;
}

// ---------------- GEMM: new_emb = feats @ W + b  (f32, vector ALU) ----------
// block = 256 threads, BM=64 rows x all 128 cols, BK=32.
// As stored transposed [k][row] with pad 65 -> A-reads conflict-free;
// Ws [k][col], b128 reads 2-way (free).
__global__ __launch_bounds__(256) void gemm_kernel(const float* __restrict__ feats,
                                                   const float* __restrict__ W,
                                                   const float* __restrict__ b,
                                                   float* __restrict__ new_emb) {
  __shared__ float As[32][65];     // 8.3 KB
  __shared__ float Ws[32][128];    // 16 KB
  const int t = threadIdx.x;
  const int row0 = blockIdx.x * 64;
  const int tx = t & 15;           // col group: cols [tx*4, tx*4+3] and [64+tx*4, ...]
  const int ty = t >> 4;           // row group: rows ty*4 .. ty*4+3

  float acc[4][8];
#pragma unroll
  for (int i = 0; i < 4; i++)
#pragma unroll
    for (int j = 0; j < 8; j++) acc[i][j] = 0.f;

  for (int k0 = 0; k0 < IN_DIM; k0 += 32) {
    // A tile: 64 rows x 32 k = 512 float4, 2 per thread
#pragma unroll
    for (int p = 0; p < 2; p++) {
      int id = t + p * 256;
      int row = id >> 3, c4 = id & 7;
      float4 v = make_float4(0.f, 0.f, 0.f, 0.f);
      if (row0 + row < N_NODES)
        v = *(const float4*)&feats[(size_t)(row0 + row) * IN_DIM + k0 + c4 * 4];
      As[c4 * 4 + 0][row] = v.x;
      As[c4 * 4 + 1][row] = v.y;
      As[c4 * 4 + 2][row] = v.z;
      As[c4 * 4 + 3][row] = v.w;
    }
    // W tile: 32 k x 128 = 1024 float4, 4 per thread
#pragma unroll
    for (int p = 0; p < 4; p++) {
      int id = t + p * 256;
      int kr = id >> 5, c4 = id & 31;
      *(float4*)&Ws[kr][c4 * 4] = *(const float4*)&W[(size_t)(k0 + kr) * OUT_DIM + c4 * 4];
    }
    __syncthreads();
#pragma unroll
    for (int k = 0; k < 32; k++) {
      float av[4];
#pragma unroll
      for (int i = 0; i < 4; i++) av[i] = As[k][ty * 4 + i];
      float4 w0 = *(const float4*)&Ws[k][tx * 4];
      float4 w1 = *(const float4*)&Ws[k][64 + tx * 4];
#pragma unroll
      for (int i = 0; i < 4; i++) {
        acc[i][0] += av[i] * w0.x; acc[i][1] += av[i] * w0.y;
        acc[i][2] += av[i] * w0.z; acc[i][3] += av[i] * w0.w;
        acc[i][4] += av[i] * w1.x; acc[i][5] += av[i] * w1.y;
        acc[i][6] += av[i] * w1.z; acc[i][7] += av[i] * w1.w;
      }
    }
    __syncthreads();
  }
  float4 b0 = *(const float4*)&b[tx * 4];
  float4 b1 = *(const float4*)&b[64 + tx * 4];
#pragma unroll
  for (int i = 0; i < 4; i++) {
    int row = row0 + ty * 4 + i;
    if (row < N_NODES) {
      float4 o0 = make_float4(acc[i][0] + b0.x, acc[i][1] + b0.y, acc[i][2] + b0.z, acc[i][3] + b0.w);
      float4 o1 = make_float4(acc[i][4] + b1.x, acc[i][5] + b1.y, acc[i][6] + b1.z, acc[i][7] + b1.w);
      *(float4*)&new_emb[(size_t)row * OUT_DIM + tx * 4] = o0;
      *(float4*)&new_emb[(size_t)row * OUT_DIM + 64 + tx * 4] = o1;
    }
  }
}

// ---------------- scores: s_src = new_emb @ a[:d], s_dst = new_emb @ a[d:] ---
// one wave per row; lane holds float2; dual shfl_xor reduce.
__global__ __launch_bounds__(256) void scores_kernel(const float* __restrict__ new_emb,
                                                     const float* __restrict__ a,
                                                     float* __restrict__ s_src,
                                                     float* __restrict__ s_dst) {
  int wid = (blockIdx.x * blockDim.x + threadIdx.x) >> 6;
  int lane = threadIdx.x & 63;
  if (wid >= N_NODES) return;
  float2 v  = *(const float2*)&new_emb[(size_t)wid * OUT_DIM + lane * 2];
  float2 a1 = *(const float2*)&a[lane * 2];
  float2 a2 = *(const float2*)&a[OUT_DIM + lane * 2];
  float p1 = v.x * a1.x + v.y * a1.y;
  float p2 = v.x * a2.x + v.y * a2.y;
#pragma unroll
  for (int s = 32; s > 0; s >>= 1) {
    p1 += __shfl_xor(p1, s);
    p2 += __shfl_xor(p2, s);
  }
  if (lane == 0) { s_src[wid] = p1; s_dst[wid] = p2; }
}

// ---------------- filter: keep edges whose dst-row r is in the batch --------
// wave-aggregated compaction (ballot + one atomicAdd per wave).
__global__ __launch_bounds__(256) void filter_kernel(const int* __restrict__ r, const int* __restrict__ c,
                                                     const int* __restrict__ slot,
                                                     const float* __restrict__ s_src,
                                                     const float* __restrict__ s_dst,
                                                     int* __restrict__ counter,
                                                     int* __restrict__ comp_slot, int* __restrict__ comp_c,
                                                     float* __restrict__ comp_e) {
  int i0 = blockIdx.x * blockDim.x + threadIdx.x;
  int T = gridDim.x * blockDim.x;
  int lane = threadIdx.x & 63;
  for (int base = 0; base < N_EDGES; base += T) {
    int i = base + i0;
    int sl = -1, cc = 0;
    float e = 0.f;
    if (i < N_EDGES) {
      int rr = r[i];
      sl = slot[rr];
      if (sl >= 0) {
        cc = c[i];
        float x = s_src[rr] + s_dst[cc];
        float lr = x > 0.f ? x : SLOPE * x;
        e = expf(lr);
      }
    }
    bool pred = sl >= 0;
    unsigned long long m = __ballot(pred);
    int cnt = __popcll(m);
    int boff = 0;
    if (lane == 0 && cnt) boff = atomicAdd(counter, cnt);
    boff = __shfl(boff, 0);
    if (pred) {
      int off = boff + __popcll(m & ((1ull << lane) - 1ull));
      comp_slot[off] = sl;
      comp_c[off]    = cc;
      comp_e[off]    = e;
    }
  }
}

// ---------------- aggregate: num[slot] += e * new_emb[c], denom[slot] += e --
// one wave per compacted edge; coalesced 512B gather; 2 atomics/lane.
__global__ __launch_bounds__(256) void aggregate_kernel(const float* __restrict__ new_emb,
                                                        const int* __restrict__ counter,
                                                        const int* __restrict__ comp_slot,
                                                        const int* __restrict__ comp_c,
                                                        const float* __restrict__ comp_e,
                                                        float* __restrict__ num, float* __restrict__ denom) {
  int M = counter[0];
  int wid = (blockIdx.x * blockDim.x + threadIdx.x) >> 6;
  int lane = threadIdx.x & 63;
  int nW = (gridDim.x * blockDim.x) >> 6;
  for (int idx = wid; idx < M; idx += nW) {
    int sl = comp_slot[idx];
    int cc = comp_c[idx];
    float e = comp_e[idx];
    float2 v = *(const float2*)&new_emb[(size_t)cc * OUT_DIM + lane * 2];
    atomicAdd(&num[(size_t)sl * OUT_DIM + lane * 2 + 0], e * v.x);
    atomicAdd(&num[(size_t)sl * OUT_DIM + lane * 2 + 1], e * v.y);
    if (lane == 0) atomicAdd(&denom[sl], e);
  }
}

// ---------------- final: out[i] = num[slot]/ (denom[slot]+eps) ---------------
__global__ __launch_bounds__(256) void final_kernel(const int* __restrict__ batch_idx,
                                                    const int* __restrict__ slot,
                                                    const float* __restrict__ num,
                                                    const float* __restrict__ denom,
                                                    float* __restrict__ out) {
  int tid = blockIdx.x * blockDim.x + threadIdx.x;   // BATCH_N * 32 threads
  if (tid >= BATCH_N * 32) return;
  int i = tid >> 5;
  int j4 = (tid & 31) * 4;
  int sl = slot[batch_idx[i]];
  float dinv = 1.f / (denom[sl] + EPS_V);
  float4 v = *(const float4*)&num[(size_t)sl * OUT_DIM + j4];
  *(float4*)&out[(size_t)i * OUT_DIM + j4] = make_float4(v.x * dinv, v.y * dinv, v.z * dinv, v.w * dinv);
}

extern "C" void kernel_launch(void* const* d_in, const int* in_sizes, int n_in,
                              void* d_out, int out_size, void* d_ws, size_t ws_size,
                              hipStream_t stream) {
  const float* feats     = (const float*)d_in[0];
  const float* W         = (const float*)d_in[1];
  const float* b         = (const float*)d_in[2];
  const float* a         = (const float*)d_in[3];
  const int*   r         = (const int*)d_in[4];
  const int*   c         = (const int*)d_in[5];
  const int*   batch_idx = (const int*)d_in[6];
  float* out = (float*)d_out;

  // workspace layout (all 4B elems; ~76 MB total)
  float* ws        = (float*)d_ws;
  float* new_emb   = ws;                                     // N*128      (51.2 MB)
  float* s_src     = new_emb + (size_t)N_NODES * OUT_DIM;    // N
  float* s_dst     = s_src + N_NODES;                        // N
  int*   slot      = (int*)(s_dst + N_NODES);                // N
  float* num       = (float*)(slot + N_NODES);               // 8192*128   (4 MB)
  float* denom     = num + (size_t)BATCH_N * OUT_DIM;        // 8192
  int*   counter   = (int*)(denom + BATCH_N);                // 8 (1 used)
  int*   comp_slot = counter + 8;                            // E
  int*   comp_c    = comp_slot + N_EDGES;                    // E
  float* comp_e    = (float*)(comp_c + N_EDGES);             // E

  init_kernel<<<2048, 256, 0, stream>>>(slot, num, denom, counter);
  slots_kernel<<<(BATCH_N + 255) / 256, 256, 0, stream>>>(batch_idx, slot);
  gemm_kernel<<<(N_NODES + 63) / 64, 256, 0, stream>>>(feats, W, b, new_emb);
  scores_kernel<<<(N_NODES * 64 + 255) / 256, 256, 0, stream>>>(new_emb, a, s_src, s_dst);
  filter_kernel<<<2048, 256, 0, stream>>>(r, c, slot, s_src, s_dst, counter, comp_slot, comp_c, comp_e);
  aggregate_kernel<<<2048, 256, 0, stream>>>(new_emb, counter, comp_slot, comp_c, comp_e, num, denom);
  final_kernel<<<(BATCH_N * 32 + 255) / 256, 256, 0, stream>>>(batch_idx, slot, num, denom, out);
}

// Round 2
// 303.429 us; speedup vs baseline: 2.1282x; 2.1282x over previous
//
#include <hip/hip_runtime.h>

#define N_NODES 100000
#define N_EDGES 1600000
#define IN_DIM  256
#define OUT_DIM 128
#define BATCH_N 8192
#define SLOPE   0.1f
#define EPS_V   1e-8f

// ---------------- init: slot=-1, slot_count=0, cursor=0 ----------------
__global__ __launch_bounds__(256) void init_kernel(int* __restrict__ slot, int* __restrict__ slot_count,
                                                   int* __restrict__ cursor) {
  int i = blockIdx.x * blockDim.x + threadIdx.x;
  if (i < N_NODES) slot[i] = -1;
  if (i < BATCH_N) { slot_count[i] = 0; cursor[i] = 0; }
}

// ---------------- slots: node -> slot map (duplicate-node races benign:
// one aligned-32b writer wins; all readers see the same winner)
__global__ __launch_bounds__(256) void slots_kernel(const int* __restrict__ batch_idx, int* __restrict__ slot) {
  int i = blockIdx.x * blockDim.x + threadIdx.x;
  if (i < BATCH_N) slot[batch_idx[i]] = i;
}

// ---------------- GEMM: new_emb = feats @ W + b  (f32, vector ALU) ----------
__global__ __launch_bounds__(256) void gemm_kernel(const float* __restrict__ feats,
                                                   const float* __restrict__ W,
                                                   const float* __restrict__ b,
                                                   float* __restrict__ new_emb) {
  __shared__ float As[32][65];     // transposed [k][row], pad 65 -> conflict-free
  __shared__ float Ws[32][128];
  const int t = threadIdx.x;
  const int row0 = blockIdx.x * 64;
  const int tx = t & 15;
  const int ty = t >> 4;

  float acc[4][8];
#pragma unroll
  for (int i = 0; i < 4; i++)
#pragma unroll
    for (int j = 0; j < 8; j++) acc[i][j] = 0.f;

  for (int k0 = 0; k0 < IN_DIM; k0 += 32) {
#pragma unroll
    for (int p = 0; p < 2; p++) {
      int id = t + p * 256;
      int row = id >> 3, c4 = id & 7;
      float4 v = make_float4(0.f, 0.f, 0.f, 0.f);
      if (row0 + row < N_NODES)
        v = *(const float4*)&feats[(size_t)(row0 + row) * IN_DIM + k0 + c4 * 4];
      As[c4 * 4 + 0][row] = v.x;
      As[c4 * 4 + 1][row] = v.y;
      As[c4 * 4 + 2][row] = v.z;
      As[c4 * 4 + 3][row] = v.w;
    }
#pragma unroll
    for (int p = 0; p < 4; p++) {
      int id = t + p * 256;
      int kr = id >> 5, c4 = id & 31;
      *(float4*)&Ws[kr][c4 * 4] = *(const float4*)&W[(size_t)(k0 + kr) * OUT_DIM + c4 * 4];
    }
    __syncthreads();
#pragma unroll
    for (int k = 0; k < 32; k++) {
      float av[4];
#pragma unroll
      for (int i = 0; i < 4; i++) av[i] = As[k][ty * 4 + i];
      float4 w0 = *(const float4*)&Ws[k][tx * 4];
      float4 w1 = *(const float4*)&Ws[k][64 + tx * 4];
#pragma unroll
      for (int i = 0; i < 4; i++) {
        acc[i][0] += av[i] * w0.x; acc[i][1] += av[i] * w0.y;
        acc[i][2] += av[i] * w0.z; acc[i][3] += av[i] * w0.w;
        acc[i][4] += av[i] * w1.x; acc[i][5] += av[i] * w1.y;
        acc[i][6] += av[i] * w1.z; acc[i][7] += av[i] * w1.w;
      }
    }
    __syncthreads();
  }
  float4 b0 = *(const float4*)&b[tx * 4];
  float4 b1 = *(const float4*)&b[64 + tx * 4];
#pragma unroll
  for (int i = 0; i < 4; i++) {
    int row = row0 + ty * 4 + i;
    if (row < N_NODES) {
      float4 o0 = make_float4(acc[i][0] + b0.x, acc[i][1] + b0.y, acc[i][2] + b0.z, acc[i][3] + b0.w);
      float4 o1 = make_float4(acc[i][4] + b1.x, acc[i][5] + b1.y, acc[i][6] + b1.z, acc[i][7] + b1.w);
      *(float4*)&new_emb[(size_t)row * OUT_DIM + tx * 4] = o0;
      *(float4*)&new_emb[(size_t)row * OUT_DIM + 64 + tx * 4] = o1;
    }
  }
}

// ---------------- scores: s_src = new_emb @ a[:d], s_dst = new_emb @ a[d:] ---
__global__ __launch_bounds__(256) void scores_kernel(const float* __restrict__ new_emb,
                                                     const float* __restrict__ a,
                                                     float* __restrict__ s_src,
                                                     float* __restrict__ s_dst) {
  int wid = (blockIdx.x * blockDim.x + threadIdx.x) >> 6;
  int lane = threadIdx.x & 63;
  if (wid >= N_NODES) return;
  float2 v  = *(const float2*)&new_emb[(size_t)wid * OUT_DIM + lane * 2];
  float2 a1 = *(const float2*)&a[lane * 2];
  float2 a2 = *(const float2*)&a[OUT_DIM + lane * 2];
  float p1 = v.x * a1.x + v.y * a1.y;
  float p2 = v.x * a2.x + v.y * a2.y;
#pragma unroll
  for (int s = 32; s > 0; s >>= 1) {
    p1 += __shfl_xor(p1, s);
    p2 += __shfl_xor(p2, s);
  }
  if (lane == 0) { s_src[wid] = p1; s_dst[wid] = p2; }
}

// ---------------- count: slot_count[sl]++ for each relevant edge ------------
// atomics spread over 8192 addresses -> no same-address serialization.
__global__ __launch_bounds__(256) void count_kernel(const int* __restrict__ r, const int* __restrict__ slot,
                                                    int* __restrict__ slot_count) {
  int i = blockIdx.x * blockDim.x + threadIdx.x;
  if (i >= N_EDGES) return;
  int sl = slot[r[i]];
  if (sl >= 0) atomicAdd(&slot_count[sl], 1);
}

// ---------------- scan: exclusive prefix over 8192 counts (single block) ----
__global__ __launch_bounds__(256) void scan_kernel(const int* __restrict__ slot_count,
                                                   int* __restrict__ slot_start) {
  __shared__ int tot[256];
  int t = threadIdx.x;
  int base = t * 32;
  int local[32];
  int run = 0;
#pragma unroll
  for (int k = 0; k < 32; k++) { local[k] = run; run += slot_count[base + k]; }
  tot[t] = run;
  __syncthreads();
  for (int off = 1; off < 256; off <<= 1) {
    int v = (t >= off) ? tot[t - off] : 0;
    __syncthreads();
    tot[t] += v;
    __syncthreads();
  }
  int excl = (t == 0) ? 0 : tot[t - 1];
#pragma unroll
  for (int k = 0; k < 32; k++) slot_start[base + k] = excl + local[k];
}

// ---------------- scatter: edge -> its slot's bucket ------------------------
__global__ __launch_bounds__(256) void scatter_kernel(const int* __restrict__ r, const int* __restrict__ c,
                                                      const int* __restrict__ slot,
                                                      const float* __restrict__ s_src,
                                                      const float* __restrict__ s_dst,
                                                      const int* __restrict__ slot_start,
                                                      int* __restrict__ cursor,
                                                      int* __restrict__ bucket_c, float* __restrict__ bucket_e) {
  int i = blockIdx.x * blockDim.x + threadIdx.x;
  if (i >= N_EDGES) return;
  int rr = r[i];
  int sl = slot[rr];
  if (sl < 0) return;
  int cc = c[i];
  float x = s_src[rr] + s_dst[cc];
  float lr = x > 0.f ? x : SLOPE * x;
  float e = expf(lr);
  int pos = atomicAdd(&cursor[sl], 1);
  int idx = slot_start[sl] + pos;
  bucket_c[idx] = cc;
  bucket_e[idx] = e;
}

// ---------------- agg: wave per slot, zero atomics, fused divide ------------
__global__ __launch_bounds__(256) void agg_kernel(const float* __restrict__ new_emb,
                                                  const int* __restrict__ slot_start,
                                                  const int* __restrict__ slot_count,
                                                  const int* __restrict__ bucket_c,
                                                  const float* __restrict__ bucket_e,
                                                  float* __restrict__ res) {
  int wid = (blockIdx.x * blockDim.x + threadIdx.x) >> 6;
  int lane = threadIdx.x & 63;
  if (wid >= BATCH_N) return;
  int start = slot_start[wid];
  int cnt = slot_count[wid];
  float ax = 0.f, ay = 0.f, den = 0.f;
  for (int j = 0; j < cnt; j++) {
    int cc = bucket_c[start + j];
    float e = bucket_e[start + j];
    float2 v = *(const float2*)&new_emb[(size_t)cc * OUT_DIM + lane * 2];
    ax += e * v.x;
    ay += e * v.y;
    den += e;
  }
  float dinv = 1.f / (den + EPS_V);
  *(float2*)&res[(size_t)wid * OUT_DIM + lane * 2] = make_float2(ax * dinv, ay * dinv);
}

// ---------------- final: out[i] = res[slot[batch_idx[i]]] -------------------
__global__ __launch_bounds__(256) void final_kernel(const int* __restrict__ batch_idx,
                                                    const int* __restrict__ slot,
                                                    const float* __restrict__ res,
                                                    float* __restrict__ out) {
  int tid = blockIdx.x * blockDim.x + threadIdx.x;   // BATCH_N * 32 threads
  if (tid >= BATCH_N * 32) return;
  int i = tid >> 5;
  int j4 = (tid & 31) * 4;
  int sl = slot[batch_idx[i]];
  float4 v = *(const float4*)&res[(size_t)sl * OUT_DIM + j4];
  *(float4*)&out[(size_t)i * OUT_DIM + j4] = v;
}

extern "C" void kernel_launch(void* const* d_in, const int* in_sizes, int n_in,
                              void* d_out, int out_size, void* d_ws, size_t ws_size,
                              hipStream_t stream) {
  const float* feats     = (const float*)d_in[0];
  const float* W         = (const float*)d_in[1];
  const float* b         = (const float*)d_in[2];
  const float* a         = (const float*)d_in[3];
  const int*   r         = (const int*)d_in[4];
  const int*   c         = (const int*)d_in[5];
  const int*   batch_idx = (const int*)d_in[6];
  float* out = (float*)d_out;

  // workspace layout (4B elems; ~70 MB total)
  float* ws         = (float*)d_ws;
  float* new_emb    = ws;                                      // N*128      (51.2 MB)
  float* s_src      = new_emb + (size_t)N_NODES * OUT_DIM;     // N
  float* s_dst      = s_src + N_NODES;                         // N
  int*   slot       = (int*)(s_dst + N_NODES);                 // N
  int*   slot_count = slot + N_NODES;                          // 8192
  int*   slot_start = slot_count + BATCH_N;                    // 8192
  int*   cursor     = slot_start + BATCH_N;                    // 8192
  float* res        = (float*)(cursor + BATCH_N);              // 8192*128   (4 MB)
  int*   bucket_c   = (int*)(res + (size_t)BATCH_N * OUT_DIM); // E          (6.4 MB)
  float* bucket_e   = (float*)(bucket_c + N_EDGES);            // E          (6.4 MB)

  init_kernel<<<(N_NODES + 255) / 256, 256, 0, stream>>>(slot, slot_count, cursor);
  slots_kernel<<<(BATCH_N + 255) / 256, 256, 0, stream>>>(batch_idx, slot);
  gemm_kernel<<<(N_NODES + 63) / 64, 256, 0, stream>>>(feats, W, b, new_emb);
  scores_kernel<<<(N_NODES * 64 + 255) / 256, 256, 0, stream>>>(new_emb, a, s_src, s_dst);
  count_kernel<<<(N_EDGES + 255) / 256, 256, 0, stream>>>(r, slot, slot_count);
  scan_kernel<<<1, 256, 0, stream>>>(slot_count, slot_start);
  scatter_kernel<<<(N_EDGES + 255) / 256, 256, 0, stream>>>(r, c, slot, s_src, s_dst,
                                                            slot_start, cursor, bucket_c, bucket_e);
  agg_kernel<<<(BATCH_N * 64 + 255) / 256, 256, 0, stream>>>(new_emb, slot_start, slot_count,
                                                             bucket_c, bucket_e, res);
  final_kernel<<<(BATCH_N * 32 + 255) / 256, 256, 0, stream>>>(batch_idx, slot, res, out);
}

// Round 3
// 249.328 us; speedup vs baseline: 2.5900x; 1.2170x over previous
//
#include <hip/hip_runtime.h>

#define N_NODES 100000
#define N_EDGES 1600000
#define IN_DIM  256
#define OUT_DIM 128
#define BATCH_N 8192
#define SLOPE   0.1f
#define EPS_V   1e-8f
#define BUCKET_CAP 96   // max fan-in per batch slot; Poisson(16) => P(>96) ~ 1e-40

typedef unsigned int uint;
typedef unsigned short ushort_t;
typedef __attribute__((ext_vector_type(8))) unsigned short u16x8;
typedef __attribute__((ext_vector_type(4))) unsigned short u16x4;
typedef __attribute__((ext_vector_type(8))) __bf16 bf16x8;
typedef __attribute__((ext_vector_type(4))) float f32x4;

__device__ inline unsigned short f2bf(float x) {   // f32 -> bf16 bits, round-nearest-even
  uint u = __builtin_bit_cast(uint, x);
  return (unsigned short)((u + 0x7fffu + ((u >> 16) & 1u)) >> 16);
}
__device__ inline float bf2f(unsigned short s) {
  return __builtin_bit_cast(float, ((uint)s) << 16);
}

#define MFMA_BF16(a, b, c) __builtin_amdgcn_mfma_f32_16x16x32_bf16( \
    __builtin_bit_cast(bf16x8, (a)), __builtin_bit_cast(bf16x8, (b)), (c), 0, 0, 0)

// ---------------- prep: W [256][128] f32 -> Wt_h/Wt_l [128][256] bf16 -------
__global__ __launch_bounds__(256) void prep_kernel(const float* __restrict__ W,
                                                   unsigned short* __restrict__ Wt_h,
                                                   unsigned short* __restrict__ Wt_l) {
  int tid = blockIdx.x * 256 + threadIdx.x;
  if (tid >= IN_DIM * OUT_DIM) return;
  int k = tid >> 7, col = tid & 127;
  float x = W[tid];                       // W[k*128+col]
  unsigned short h = f2bf(x);
  unsigned short l = f2bf(x - bf2f(h));
  Wt_h[col * IN_DIM + k] = h;
  Wt_l[col * IN_DIM + k] = l;
}

// ---------------- init: slot=-1, cursor=0 -----------------------------------
__global__ __launch_bounds__(256) void init_kernel(int* __restrict__ slot, int* __restrict__ cursor) {
  int i = blockIdx.x * blockDim.x + threadIdx.x;
  if (i < N_NODES) slot[i] = -1;
  if (i < BATCH_N) cursor[i] = 0;
}

// ---------------- slots: node -> slot (duplicate races benign: one winner) --
__global__ __launch_bounds__(256) void slots_kernel(const int* __restrict__ batch_idx, int* __restrict__ slot) {
  int i = blockIdx.x * blockDim.x + threadIdx.x;
  if (i < BATCH_N) slot[batch_idx[i]] = i;
}

// ---------------- GEMM (split-bf16 MFMA) + fused scores ---------------------
// block 256 = 4 waves; BM=64 rows, BK=32. Wave w: all 64 rows x cols [32w,32w+32).
// 3-MFMA emulation: AhiBhi + AloBhi + AhiBlo => ~f32 accuracy.
__global__ __launch_bounds__(256) void gemm_kernel(const float* __restrict__ feats,
                                                   const unsigned short* __restrict__ Wt_h,
                                                   const unsigned short* __restrict__ Wt_l,
                                                   const float* __restrict__ b,
                                                   const float* __restrict__ a,
                                                   float* __restrict__ new_emb,
                                                   float* __restrict__ s_src,
                                                   float* __restrict__ s_dst) {
  __shared__ unsigned short Ah[64][40], Al[64][40];    // pad 40: 80B stride, 16B-aligned, 2-way banks
  __shared__ unsigned short Bh[128][40], Bl[128][40];  // 30 KB total -> 5 blocks/CU
  const int t = threadIdx.x;
  const int w = t >> 6, lane = t & 63;
  const int l15 = lane & 15, kg = (lane >> 4) * 8;
  const int row0 = blockIdx.x * 64;

  f32x4 acc[4][2];
#pragma unroll
  for (int m = 0; m < 4; m++)
#pragma unroll
    for (int nl = 0; nl < 2; nl++) acc[m][nl] = (f32x4)0.f;

  for (int k0 = 0; k0 < IN_DIM; k0 += 32) {
    // stage A: 64 rows x 32 k, f32 -> hi/lo bf16
#pragma unroll
    for (int p = 0; p < 2; p++) {
      int id = t + p * 256;
      int row = id >> 3, c4 = id & 7;
      float4 v = make_float4(0.f, 0.f, 0.f, 0.f);
      if (row0 + row < N_NODES)
        v = *(const float4*)&feats[(size_t)(row0 + row) * IN_DIM + k0 + c4 * 4];
      unsigned short h0 = f2bf(v.x), h1 = f2bf(v.y), h2 = f2bf(v.z), h3 = f2bf(v.w);
      u16x4 hh = {h0, h1, h2, h3};
      u16x4 ll = {f2bf(v.x - bf2f(h0)), f2bf(v.y - bf2f(h1)),
                  f2bf(v.z - bf2f(h2)), f2bf(v.w - bf2f(h3))};
      *(u16x4*)&Ah[row][c4 * 4] = hh;
      *(u16x4*)&Al[row][c4 * 4] = ll;
    }
    // stage B: 128 cols x 32 k from pre-split global planes
#pragma unroll
    for (int p = 0; p < 2; p++) {
      int id = t + p * 256;
      int col = id >> 2, kc = id & 3;
      *(u16x8*)&Bh[col][kc * 8] = *(const u16x8*)&Wt_h[col * IN_DIM + k0 + kc * 8];
      *(u16x8*)&Bl[col][kc * 8] = *(const u16x8*)&Wt_l[col * IN_DIM + k0 + kc * 8];
    }
    __syncthreads();

    u16x8 bhf[2], blf[2];
#pragma unroll
    for (int nl = 0; nl < 2; nl++) {
      int col = w * 32 + nl * 16 + l15;
      bhf[nl] = *(u16x8*)&Bh[col][kg];
      blf[nl] = *(u16x8*)&Bl[col][kg];
    }
#pragma unroll
    for (int m = 0; m < 4; m++) {
      u16x8 ah = *(u16x8*)&Ah[m * 16 + l15][kg];
      u16x8 al = *(u16x8*)&Al[m * 16 + l15][kg];
#pragma unroll
      for (int nl = 0; nl < 2; nl++) {
        acc[m][nl] = MFMA_BF16(ah, bhf[nl], acc[m][nl]);
        acc[m][nl] = MFMA_BF16(al, bhf[nl], acc[m][nl]);
        acc[m][nl] = MFMA_BF16(ah, blf[nl], acc[m][nl]);
      }
    }
    __syncthreads();
  }

  // epilogue: bias add, C-write, fused scores (s = new_emb . a halves)
  float bv[2], a1v[2], a2v[2];
#pragma unroll
  for (int nl = 0; nl < 2; nl++) {
    int col = w * 32 + nl * 16 + l15;
    bv[nl]  = b[col];
    a1v[nl] = a[col];
    a2v[nl] = a[OUT_DIM + col];
  }
  float* sp = (float*)&Ah[0][0];   // reuse LDS: sp1[4][64] at 0, sp2[4][64] at +256
#pragma unroll
  for (int m = 0; m < 4; m++) {
#pragma unroll
    for (int reg = 0; reg < 4; reg++) {
      int lrow = m * 16 + (lane >> 4) * 4 + reg;
      int grow = row0 + lrow;
      float v0 = acc[m][0][reg] + bv[0];
      float v1 = acc[m][1][reg] + bv[1];
      if (grow < N_NODES) {
        new_emb[(size_t)grow * OUT_DIM + w * 32 + l15]      = v0;
        new_emb[(size_t)grow * OUT_DIM + w * 32 + 16 + l15] = v1;
      }
      float p1 = v0 * a1v[0] + v1 * a1v[1];
      float p2 = v0 * a2v[0] + v1 * a2v[1];
#pragma unroll
      for (int s = 1; s < 16; s <<= 1) { p1 += __shfl_xor(p1, s); p2 += __shfl_xor(p2, s); }
      if (l15 == 0) { sp[w * 64 + lrow] = p1; sp[256 + w * 64 + lrow] = p2; }
    }
  }
  __syncthreads();
  if (t < 64) {
    int grow = row0 + t;
    if (grow < N_NODES) {
      s_src[grow] = sp[t] + sp[64 + t] + sp[128 + t] + sp[192 + t];
      s_dst[grow] = sp[256 + t] + sp[320 + t] + sp[384 + t] + sp[448 + t];
    }
  }
}

// ---------------- scatter: relevant edges -> fixed-cap slot buckets ---------
__global__ __launch_bounds__(256) void scatter_kernel(const int* __restrict__ r, const int* __restrict__ c,
                                                      const int* __restrict__ slot,
                                                      const float* __restrict__ s_src,
                                                      const float* __restrict__ s_dst,
                                                      int* __restrict__ cursor,
                                                      int* __restrict__ bucket_c, float* __restrict__ bucket_e) {
  int i = blockIdx.x * blockDim.x + threadIdx.x;
  if (i >= N_EDGES) return;
  int rr = r[i];
  int sl = slot[rr];
  if (sl < 0) return;
  int cc = c[i];
  float x = s_src[rr] + s_dst[cc];
  float lr = x > 0.f ? x : SLOPE * x;
  float e = expf(lr);
  int pos = atomicAdd(&cursor[sl], 1);
  if (pos < BUCKET_CAP) {
    bucket_c[sl * BUCKET_CAP + pos] = cc;
    bucket_e[sl * BUCKET_CAP + pos] = e;
  }
}

// ---------------- agg: wave per slot, zero atomics, fused divide, -> out ----
__global__ __launch_bounds__(256) void agg_kernel(const float* __restrict__ new_emb,
                                                  const int* __restrict__ cursor,
                                                  const int* __restrict__ bucket_c,
                                                  const float* __restrict__ bucket_e,
                                                  float* __restrict__ out) {
  int wid = (blockIdx.x * blockDim.x + threadIdx.x) >> 6;
  int lane = threadIdx.x & 63;
  if (wid >= BATCH_N) return;
  int cnt = cursor[wid];
  cnt = cnt > BUCKET_CAP ? BUCKET_CAP : cnt;
  int base = wid * BUCKET_CAP;
  float ax = 0.f, ay = 0.f, den = 0.f;
  for (int j = 0; j < cnt; j++) {
    int cc   = bucket_c[base + j];
    float e  = bucket_e[base + j];
    float2 v = *(const float2*)&new_emb[(size_t)cc * OUT_DIM + lane * 2];
    ax += e * v.x;
    ay += e * v.y;
    den += e;
  }
  float dinv = 1.f / (den + EPS_V);
  *(float2*)&out[(size_t)wid * OUT_DIM + lane * 2] = make_float2(ax * dinv, ay * dinv);
}

// ---------------- fix: duplicate batch rows copy the winner's row -----------
__global__ __launch_bounds__(256) void fix_kernel(const int* __restrict__ batch_idx,
                                                  const int* __restrict__ slot,
                                                  float* __restrict__ out) {
  int wid = (blockIdx.x * blockDim.x + threadIdx.x) >> 6;
  int lane = threadIdx.x & 63;
  if (wid >= BATCH_N) return;
  int sl = slot[batch_idx[wid]];
  if (sl == wid) return;
  float2 v = *(const float2*)&out[(size_t)sl * OUT_DIM + lane * 2];
  *(float2*)&out[(size_t)wid * OUT_DIM + lane * 2] = v;
}

extern "C" void kernel_launch(void* const* d_in, const int* in_sizes, int n_in,
                              void* d_out, int out_size, void* d_ws, size_t ws_size,
                              hipStream_t stream) {
  const float* feats     = (const float*)d_in[0];
  const float* W         = (const float*)d_in[1];
  const float* b         = (const float*)d_in[2];
  const float* a         = (const float*)d_in[3];
  const int*   r         = (const int*)d_in[4];
  const int*   c         = (const int*)d_in[5];
  const int*   batch_idx = (const int*)d_in[6];
  float* out = (float*)d_out;

  // workspace layout (~59 MB)
  unsigned short* Wt_h   = (unsigned short*)d_ws;                       // 128*256 bf16
  unsigned short* Wt_l   = Wt_h + IN_DIM * OUT_DIM;                     // 128*256 bf16
  float* new_emb  = (float*)(Wt_l + IN_DIM * OUT_DIM);                  // N*128  (51.2 MB)
  float* s_src    = new_emb + (size_t)N_NODES * OUT_DIM;                // N
  float* s_dst    = s_src + N_NODES;                                    // N
  int*   slot     = (int*)(s_dst + N_NODES);                            // N
  int*   cursor   = slot + N_NODES;                                     // 8192
  int*   bucket_c = cursor + BATCH_N;                                   // 8192*96 (3.1 MB)
  float* bucket_e = (float*)(bucket_c + (size_t)BATCH_N * BUCKET_CAP);  // 8192*96 (3.1 MB)

  prep_kernel<<<(IN_DIM * OUT_DIM + 255) / 256, 256, 0, stream>>>(W, Wt_h, Wt_l);
  init_kernel<<<(N_NODES + 255) / 256, 256, 0, stream>>>(slot, cursor);
  slots_kernel<<<(BATCH_N + 255) / 256, 256, 0, stream>>>(batch_idx, slot);
  gemm_kernel<<<(N_NODES + 63) / 64, 256, 0, stream>>>(feats, Wt_h, Wt_l, b, a,
                                                       new_emb, s_src, s_dst);
  scatter_kernel<<<(N_EDGES + 255) / 256, 256, 0, stream>>>(r, c, slot, s_src, s_dst,
                                                            cursor, bucket_c, bucket_e);
  agg_kernel<<<(BATCH_N * 64 + 255) / 256, 256, 0, stream>>>(new_emb, cursor, bucket_c, bucket_e, out);
  fix_kernel<<<(BATCH_N * 64 + 255) / 256, 256, 0, stream>>>(batch_idx, slot, out);
}

// Round 4
// 246.098 us; speedup vs baseline: 2.6240x; 1.0131x over previous
//
#include <hip/hip_runtime.h>

#define N_NODES 100000
#define N_EDGES 1600000
#define IN_DIM  256
#define OUT_DIM 128
#define BATCH_N 8192
#define SLOPE   0.1f
#define EPS_V   1e-8f
#define BUCKET_CAP 96   // max fan-in per slot; Poisson(16) => P(>96) ~ 1e-40

// ---------------- prep: u = W@a1, v = W@a2 (256 each), cu = b.a1, cv = b.a2 --
__global__ __launch_bounds__(256) void prep_kernel(const float* __restrict__ W,
                                                   const float* __restrict__ b,
                                                   const float* __restrict__ a,
                                                   float* __restrict__ uv,      // [512]
                                                   float* __restrict__ consts) { // [2]
  int t = threadIdx.x;                 // one thread per k
  float su = 0.f, sv = 0.f;
  for (int j = 0; j < OUT_DIM; j++) {
    float w = W[t * OUT_DIM + j];
    su += w * a[j];
    sv += w * a[OUT_DIM + j];
  }
  uv[t] = su;
  uv[IN_DIM + t] = sv;

  __shared__ float red[256];
  float pb = (t < OUT_DIM) ? b[t] : 0.f;
  red[t] = (t < OUT_DIM) ? pb * a[t] : 0.f;
  __syncthreads();
  for (int off = 128; off > 0; off >>= 1) {
    if (t < off) red[t] += red[t + off];
    __syncthreads();
  }
  if (t == 0) consts[0] = red[0];
  __syncthreads();
  red[t] = (t < OUT_DIM) ? pb * a[OUT_DIM + t] : 0.f;
  __syncthreads();
  for (int off = 128; off > 0; off >>= 1) {
    if (t < off) red[t] += red[t + off];
    __syncthreads();
  }
  if (t == 0) consts[1] = red[0];
}

// ---------------- init: slot=-1, cursor=0 -----------------------------------
__global__ __launch_bounds__(256) void init_kernel(int* __restrict__ slot, int* __restrict__ cursor) {
  int i = blockIdx.x * blockDim.x + threadIdx.x;
  if (i < N_NODES) slot[i] = -1;
  if (i < BATCH_N) cursor[i] = 0;
}

// ---------------- slots: node -> slot (duplicate races benign: one winner) --
__global__ __launch_bounds__(256) void slots_kernel(const int* __restrict__ batch_idx, int* __restrict__ slot) {
  int i = blockIdx.x * blockDim.x + threadIdx.x;
  if (i < BATCH_N) slot[batch_idx[i]] = i;
}

// ---------------- scores: one streaming pass over feats ---------------------
// s_src[i] = feats[i].u + cu ; s_dst[i] = feats[i].v + cv. Wave per node.
__global__ __launch_bounds__(256) void scores_kernel(const float* __restrict__ feats,
                                                     const float* __restrict__ uv,
                                                     const float* __restrict__ consts,
                                                     float* __restrict__ s_src,
                                                     float* __restrict__ s_dst) {
  int wid = (blockIdx.x * blockDim.x + threadIdx.x) >> 6;
  int lane = threadIdx.x & 63;
  if (wid >= N_NODES) return;
  float4 f  = *(const float4*)&feats[(size_t)wid * IN_DIM + lane * 4];
  float4 u4 = *(const float4*)&uv[lane * 4];
  float4 v4 = *(const float4*)&uv[IN_DIM + lane * 4];
  float p1 = f.x * u4.x + f.y * u4.y + f.z * u4.z + f.w * u4.w;
  float p2 = f.x * v4.x + f.y * v4.y + f.z * v4.z + f.w * v4.w;
#pragma unroll
  for (int s = 32; s > 0; s >>= 1) {
    p1 += __shfl_xor(p1, s);
    p2 += __shfl_xor(p2, s);
  }
  if (lane == 0) {
    s_src[wid] = p1 + consts[0];
    s_dst[wid] = p2 + consts[1];
  }
}

// ---------------- scatter: relevant edges -> fixed-cap slot buckets ---------
__global__ __launch_bounds__(256) void scatter_kernel(const int* __restrict__ r, const int* __restrict__ c,
                                                      const int* __restrict__ slot,
                                                      const float* __restrict__ s_src,
                                                      const float* __restrict__ s_dst,
                                                      int* __restrict__ cursor,
                                                      int* __restrict__ bucket_c, float* __restrict__ bucket_e) {
  int i = blockIdx.x * blockDim.x + threadIdx.x;
  if (i >= N_EDGES) return;
  int rr = r[i];
  int sl = slot[rr];
  if (sl < 0) return;
  int cc = c[i];
  float x = s_src[rr] + s_dst[cc];
  float lr = x > 0.f ? x : SLOPE * x;
  float e = expf(lr);
  int pos = atomicAdd(&cursor[sl], 1);
  if (pos < BUCKET_CAP) {
    bucket_c[sl * BUCKET_CAP + pos] = cc;
    bucket_e[sl * BUCKET_CAP + pos] = e;
  }
}

// ---------------- agg: wave per slot, gather RAW feats (256-d), fused norm --
// aggw[sl] = (Sum e*feats[c]) / (den+eps), scale_b[sl] = den/(den+eps)
__global__ __launch_bounds__(256) void agg_kernel(const float* __restrict__ feats,
                                                  const int* __restrict__ cursor,
                                                  const int* __restrict__ bucket_c,
                                                  const float* __restrict__ bucket_e,
                                                  float* __restrict__ aggw,
                                                  float* __restrict__ scale_b) {
  int wid = (blockIdx.x * blockDim.x + threadIdx.x) >> 6;
  int lane = threadIdx.x & 63;
  if (wid >= BATCH_N) return;
  int cnt = cursor[wid];
  cnt = cnt > BUCKET_CAP ? BUCKET_CAP : cnt;
  int base = wid * BUCKET_CAP;
  float ax = 0.f, ay = 0.f, az = 0.f, aw = 0.f, den = 0.f;
#pragma unroll 2
  for (int j = 0; j < cnt; j++) {
    int cc  = bucket_c[base + j];
    float e = bucket_e[base + j];
    float4 f = *(const float4*)&feats[(size_t)cc * IN_DIM + lane * 4];
    ax += e * f.x; ay += e * f.y; az += e * f.z; aw += e * f.w;
    den += e;                         // uniform across lanes, no reduce needed
  }
  float dinv = 1.f / (den + EPS_V);
  *(float4*)&aggw[(size_t)wid * IN_DIM + lane * 4] =
      make_float4(ax * dinv, ay * dinv, az * dinv, aw * dinv);
  if (lane == 0) scale_b[wid] = den * dinv;
}

// ---------------- gemm2: out[sl] = aggw[sl] @ W + scale_b[sl]*b -------------
// [8192 x 256] @ [256 x 128]; BM=32, BK=32, block=256 -> 256 blocks.
__global__ __launch_bounds__(256) void gemm2_kernel(const float* __restrict__ aggw,
                                                    const float* __restrict__ W,
                                                    const float* __restrict__ b,
                                                    const float* __restrict__ scale_b,
                                                    float* __restrict__ out) {
  __shared__ float As[32][33];     // transposed [k][row]
  __shared__ float Ws[32][128];
  const int t = threadIdx.x;
  const int row0 = blockIdx.x * 32;
  const int tx = t & 31;           // cols tx*4 .. +3
  const int ty = t >> 5;           // rows ty*4 .. +3

  float acc[4][4];
#pragma unroll
  for (int i = 0; i < 4; i++)
#pragma unroll
    for (int j = 0; j < 4; j++) acc[i][j] = 0.f;

  for (int k0 = 0; k0 < IN_DIM; k0 += 32) {
    {
      int row = t >> 3, c4 = t & 7;   // 32 rows x 8 float4
      float4 v = *(const float4*)&aggw[(size_t)(row0 + row) * IN_DIM + k0 + c4 * 4];
      As[c4 * 4 + 0][row] = v.x;
      As[c4 * 4 + 1][row] = v.y;
      As[c4 * 4 + 2][row] = v.z;
      As[c4 * 4 + 3][row] = v.w;
    }
#pragma unroll
    for (int p = 0; p < 4; p++) {
      int id = t + p * 256;
      int kr = id >> 5, c4 = id & 31;
      *(float4*)&Ws[kr][c4 * 4] = *(const float4*)&W[(size_t)(k0 + kr) * OUT_DIM + c4 * 4];
    }
    __syncthreads();
#pragma unroll
    for (int k = 0; k < 32; k++) {
      float av[4];
#pragma unroll
      for (int i = 0; i < 4; i++) av[i] = As[k][ty * 4 + i];
      float4 w4 = *(const float4*)&Ws[k][tx * 4];
#pragma unroll
      for (int i = 0; i < 4; i++) {
        acc[i][0] += av[i] * w4.x; acc[i][1] += av[i] * w4.y;
        acc[i][2] += av[i] * w4.z; acc[i][3] += av[i] * w4.w;
      }
    }
    __syncthreads();
  }
  float4 b4 = *(const float4*)&b[tx * 4];
#pragma unroll
  for (int i = 0; i < 4; i++) {
    int row = row0 + ty * 4 + i;
    float sb = scale_b[row];
    *(float4*)&out[(size_t)row * OUT_DIM + tx * 4] =
        make_float4(acc[i][0] + sb * b4.x, acc[i][1] + sb * b4.y,
                    acc[i][2] + sb * b4.z, acc[i][3] + sb * b4.w);
  }
}

// ---------------- fix: duplicate batch rows copy the winner's row -----------
__global__ __launch_bounds__(256) void fix_kernel(const int* __restrict__ batch_idx,
                                                  const int* __restrict__ slot,
                                                  float* __restrict__ out) {
  int wid = (blockIdx.x * blockDim.x + threadIdx.x) >> 6;
  int lane = threadIdx.x & 63;
  if (wid >= BATCH_N) return;
  int sl = slot[batch_idx[wid]];
  if (sl == wid) return;
  float2 v = *(const float2*)&out[(size_t)sl * OUT_DIM + lane * 2];
  *(float2*)&out[(size_t)wid * OUT_DIM + lane * 2] = v;
}

extern "C" void kernel_launch(void* const* d_in, const int* in_sizes, int n_in,
                              void* d_out, int out_size, void* d_ws, size_t ws_size,
                              hipStream_t stream) {
  const float* feats     = (const float*)d_in[0];
  const float* W         = (const float*)d_in[1];
  const float* b         = (const float*)d_in[2];
  const float* a         = (const float*)d_in[3];
  const int*   r         = (const int*)d_in[4];
  const int*   c         = (const int*)d_in[5];
  const int*   batch_idx = (const int*)d_in[6];
  float* out = (float*)d_out;

  // workspace layout (~16 MB)
  float* uv       = (float*)d_ws;                                       // 512
  float* consts   = uv + 2 * IN_DIM;                                    // 8
  float* s_src    = consts + 8;                                         // N
  float* s_dst    = s_src + N_NODES;                                    // N
  int*   slot     = (int*)(s_dst + N_NODES);                            // N
  int*   cursor   = slot + N_NODES;                                     // 8192
  float* scale_b  = (float*)(cursor + BATCH_N);                         // 8192
  int*   bucket_c = (int*)(scale_b + BATCH_N);                          // 8192*96 (3.1 MB)
  float* bucket_e = (float*)(bucket_c + (size_t)BATCH_N * BUCKET_CAP);  // 3.1 MB
  float* aggw     = bucket_e + (size_t)BATCH_N * BUCKET_CAP;            // 8192*256 (8 MB)

  prep_kernel<<<1, 256, 0, stream>>>(W, b, a, uv, consts);
  init_kernel<<<(N_NODES + 255) / 256, 256, 0, stream>>>(slot, cursor);
  slots_kernel<<<(BATCH_N + 255) / 256, 256, 0, stream>>>(batch_idx, slot);
  scores_kernel<<<(N_NODES * 64 + 255) / 256, 256, 0, stream>>>(feats, uv, consts, s_src, s_dst);
  scatter_kernel<<<(N_EDGES + 255) / 256, 256, 0, stream>>>(r, c, slot, s_src, s_dst,
                                                            cursor, bucket_c, bucket_e);
  agg_kernel<<<(BATCH_N * 64 + 255) / 256, 256, 0, stream>>>(feats, cursor, bucket_c, bucket_e,
                                                             aggw, scale_b);
  gemm2_kernel<<<BATCH_N / 32, 256, 0, stream>>>(aggw, W, b, scale_b, out);
  fix_kernel<<<(BATCH_N * 64 + 255) / 256, 256, 0, stream>>>(batch_idx, slot, out);
}

// Round 6
// 245.124 us; speedup vs baseline: 2.6344x; 1.0040x over previous
//
#include <hip/hip_runtime.h>

#define N_NODES 100000
#define N_EDGES 1600000
#define IN_DIM  256
#define OUT_DIM 128
#define BATCH_N 8192
#define SLOPE   0.1f
#define EPS_V   1e-8f
#define BUCKET_CAP 96   // max fan-in per slot; Poisson(16) => P(>96) ~ 1e-40

// ---------------- prep: u = W@a1, v = W@a2 (256 each), cu = b.a1, cv = b.a2 --
__global__ __launch_bounds__(256) void prep_kernel(const float* __restrict__ W,
                                                   const float* __restrict__ b,
                                                   const float* __restrict__ a,
                                                   float* __restrict__ uv,       // [512]
                                                   float* __restrict__ consts) { // [2]
  int t = threadIdx.x;                 // one thread per k
  float su = 0.f, sv = 0.f;
  for (int j = 0; j < OUT_DIM; j++) {
    float w = W[t * OUT_DIM + j];
    su += w * a[j];
    sv += w * a[OUT_DIM + j];
  }
  uv[t] = su;
  uv[IN_DIM + t] = sv;

  __shared__ float red[256];
  float pb = (t < OUT_DIM) ? b[t] : 0.f;
  red[t] = (t < OUT_DIM) ? pb * a[t] : 0.f;
  __syncthreads();
  for (int off = 128; off > 0; off >>= 1) {
    if (t < off) red[t] += red[t + off];
    __syncthreads();
  }
  if (t == 0) consts[0] = red[0];
  __syncthreads();
  red[t] = (t < OUT_DIM) ? pb * a[OUT_DIM + t] : 0.f;
  __syncthreads();
  for (int off = 128; off > 0; off >>= 1) {
    if (t < off) red[t] += red[t + off];
    __syncthreads();
  }
  if (t == 0) consts[1] = red[0];
}

// ---------------- init: slot=-1, cursor=0 -----------------------------------
__global__ __launch_bounds__(256) void init_kernel(int* __restrict__ slot, int* __restrict__ cursor) {
  int i = blockIdx.x * blockDim.x + threadIdx.x;
  if (i < N_NODES) slot[i] = -1;
  if (i < BATCH_N) cursor[i] = 0;
}

// ---------------- slots: node -> slot (duplicate races benign: one winner) --
__global__ __launch_bounds__(256) void slots_kernel(const int* __restrict__ batch_idx, int* __restrict__ slot) {
  int i = blockIdx.x * blockDim.x + threadIdx.x;
  if (i < BATCH_N) slot[batch_idx[i]] = i;
}

// ---------------- scores: one streaming pass over feats ---------------------
// s_src[i] = feats[i].u + cu ; s_dst[i] = feats[i].v + cv. Wave per node.
__global__ __launch_bounds__(256) void scores_kernel(const float* __restrict__ feats,
                                                     const float* __restrict__ uv,
                                                     const float* __restrict__ consts,
                                                     float* __restrict__ s_src,
                                                     float* __restrict__ s_dst) {
  int wid = (blockIdx.x * blockDim.x + threadIdx.x) >> 6;
  int lane = threadIdx.x & 63;
  if (wid >= N_NODES) return;
  float4 f  = *(const float4*)&feats[(size_t)wid * IN_DIM + lane * 4];
  float4 u4 = *(const float4*)&uv[lane * 4];
  float4 v4 = *(const float4*)&uv[IN_DIM + lane * 4];
  float p1 = f.x * u4.x + f.y * u4.y + f.z * u4.z + f.w * u4.w;
  float p2 = f.x * v4.x + f.y * v4.y + f.z * v4.z + f.w * v4.w;
#pragma unroll
  for (int s = 32; s > 0; s >>= 1) {
    p1 += __shfl_xor(p1, s);
    p2 += __shfl_xor(p2, s);
  }
  if (lane == 0) {
    s_src[wid] = p1 + consts[0];
    s_dst[wid] = p2 + consts[1];
  }
}

// ---------------- scatter: relevant edges -> fixed-cap slot buckets ---------
__global__ __launch_bounds__(256) void scatter_kernel(const int* __restrict__ r, const int* __restrict__ c,
                                                      const int* __restrict__ slot,
                                                      const float* __restrict__ s_src,
                                                      const float* __restrict__ s_dst,
                                                      int* __restrict__ cursor,
                                                      int* __restrict__ bucket_c, float* __restrict__ bucket_e) {
  int i = blockIdx.x * blockDim.x + threadIdx.x;
  if (i >= N_EDGES) return;
  int rr = r[i];
  int sl = slot[rr];
  if (sl < 0) return;
  int cc = c[i];
  float x = s_src[rr] + s_dst[cc];
  float lr = x > 0.f ? x : SLOPE * x;
  float e = expf(lr);
  int pos = atomicAdd(&cursor[sl], 1);
  if (pos < BUCKET_CAP) {
    bucket_c[sl * BUCKET_CAP + pos] = cc;
    bucket_e[sl * BUCKET_CAP + pos] = e;
  }
}

// ---------------- agg: BLOCK (4 waves) per slot -----------------------------
// Buckets staged in LDS (indices off the global dependent chain), edges split
// across waves (straggler tail /4, 8x outstanding gathers), LDS combine,
// fused divide. aggw[sl] = (Sum e*feats[c])/(den+eps), scale_b = den/(den+eps).
__global__ __launch_bounds__(256) void agg_kernel(const float* __restrict__ feats,
                                                  const int* __restrict__ cursor,
                                                  const int* __restrict__ bucket_c,
                                                  const float* __restrict__ bucket_e,
                                                  float* __restrict__ aggw,
                                                  float* __restrict__ scale_b) {
  __shared__ int   sc[BUCKET_CAP];
  __shared__ float se[BUCKET_CAP];
  __shared__ float red[4][256];
  __shared__ float dred[4];
  const int sl = blockIdx.x;
  const int t = threadIdx.x, w = t >> 6, lane = t & 63;
  int cnt = cursor[sl];
  cnt = cnt > BUCKET_CAP ? BUCKET_CAP : cnt;
  if (t < cnt) {
    sc[t] = bucket_c[sl * BUCKET_CAP + t];
    se[t] = bucket_e[sl * BUCKET_CAP + t];
  }
  __syncthreads();
  float ax = 0.f, ay = 0.f, az = 0.f, aw = 0.f, den = 0.f;
#pragma unroll 2
  for (int j = w; j < cnt; j += 4) {
    int cc  = sc[j];
    float e = se[j];
    float4 f = *(const float4*)&feats[(size_t)cc * IN_DIM + lane * 4];
    ax += e * f.x; ay += e * f.y; az += e * f.z; aw += e * f.w;
    den += e;
  }
  *(float4*)&red[w][lane * 4] = make_float4(ax, ay, az, aw);
  if (lane == 0) dred[w] = den;
  __syncthreads();
  if (w == 0) {
    float4 r0 = *(float4*)&red[0][lane * 4];
    float4 r1 = *(float4*)&red[1][lane * 4];
    float4 r2 = *(float4*)&red[2][lane * 4];
    float4 r3 = *(float4*)&red[3][lane * 4];
    float d = dred[0] + dred[1] + dred[2] + dred[3];
    float dinv = 1.f / (d + EPS_V);
    *(float4*)&aggw[(size_t)sl * IN_DIM + lane * 4] =
        make_float4((r0.x + r1.x + r2.x + r3.x) * dinv,
                    (r0.y + r1.y + r2.y + r3.y) * dinv,
                    (r0.z + r1.z + r2.z + r3.z) * dinv,
                    (r0.w + r1.w + r2.w + r3.w) * dinv);
    if (lane == 0) scale_b[sl] = d * dinv;
  }
}

// ---------------- gemm2: out[sl] = aggw[sl] @ W + scale_b[sl]*b -------------
// [8192 x 256] @ [256 x 128]; BM=32, BK=32, block=256 -> 256 blocks.
__global__ __launch_bounds__(256) void gemm2_kernel(const float* __restrict__ aggw,
                                                    const float* __restrict__ W,
                                                    const float* __restrict__ b,
                                                    const float* __restrict__ scale_b,
                                                    float* __restrict__ out) {
  __shared__ float As[32][33];     // transposed [k][row]
  __shared__ float Ws[32][128];
  const int t = threadIdx.x;
  const int row0 = blockIdx.x * 32;
  const int tx = t & 31;           // cols tx*4 .. +3
  const int ty = t >> 5;           // rows ty*4 .. +3

  float acc[4][4];
#pragma unroll
  for (int i = 0; i < 4; i++)
#pragma unroll
    for (int j = 0; j < 4; j++) acc[i][j] = 0.f;

  for (int k0 = 0; k0 < IN_DIM; k0 += 32) {
    {
      int row = t >> 3, c4 = t & 7;   // 32 rows x 8 float4
      float4 v = *(const float4*)&aggw[(size_t)(row0 + row) * IN_DIM + k0 + c4 * 4];
      As[c4 * 4 + 0][row] = v.x;
      As[c4 * 4 + 1][row] = v.y;
      As[c4 * 4 + 2][row] = v.z;
      As[c4 * 4 + 3][row] = v.w;
    }
#pragma unroll
    for (int p = 0; p < 4; p++) {
      int id = t + p * 256;
      int kr = id >> 5, c4 = id & 31;
      *(float4*)&Ws[kr][c4 * 4] = *(const float4*)&W[(size_t)(k0 + kr) * OUT_DIM + c4 * 4];
    }
    __syncthreads();
#pragma unroll
    for (int k = 0; k < 32; k++) {
      float av[4];
#pragma unroll
      for (int i = 0; i < 4; i++) av[i] = As[k][ty * 4 + i];
      float4 w4 = *(const float4*)&Ws[k][tx * 4];
#pragma unroll
      for (int i = 0; i < 4; i++) {
        acc[i][0] += av[i] * w4.x; acc[i][1] += av[i] * w4.y;
        acc[i][2] += av[i] * w4.z; acc[i][3] += av[i] * w4.w;
      }
    }
    __syncthreads();
  }
  float4 b4 = *(const float4*)&b[tx * 4];
#pragma unroll
  for (int i = 0; i < 4; i++) {
    int row = row0 + ty * 4 + i;
    float sb = scale_b[row];
    *(float4*)&out[(size_t)row * OUT_DIM + tx * 4] =
        make_float4(acc[i][0] + sb * b4.x, acc[i][1] + sb * b4.y,
                    acc[i][2] + sb * b4.z, acc[i][3] + sb * b4.w);
  }
}

// ---------------- fix: duplicate batch rows copy the winner's row -----------
__global__ __launch_bounds__(256) void fix_kernel(const int* __restrict__ batch_idx,
                                                  const int* __restrict__ slot,
                                                  float* __restrict__ out) {
  int wid = (blockIdx.x * blockDim.x + threadIdx.x) >> 6;
  int lane = threadIdx.x & 63;
  if (wid >= BATCH_N) return;
  int sl = slot[batch_idx[wid]];
  if (sl == wid) return;
  float2 v = *(const float2*)&out[(size_t)sl * OUT_DIM + lane * 2];
  *(float2*)&out[(size_t)wid * OUT_DIM + lane * 2] = v;
}

extern "C" void kernel_launch(void* const* d_in, const int* in_sizes, int n_in,
                              void* d_out, int out_size, void* d_ws, size_t ws_size,
                              hipStream_t stream) {
  const float* feats     = (const float*)d_in[0];
  const float* W         = (const float*)d_in[1];
  const float* b         = (const float*)d_in[2];
  const float* a         = (const float*)d_in[3];
  const int*   r         = (const int*)d_in[4];
  const int*   c         = (const int*)d_in[5];
  const int*   batch_idx = (const int*)d_in[6];
  float* out = (float*)d_out;

  // workspace layout (~16 MB)
  float* uv       = (float*)d_ws;                                       // 512
  float* consts   = uv + 2 * IN_DIM;                                    // 8
  float* s_src    = consts + 8;                                         // N
  float* s_dst    = s_src + N_NODES;                                    // N
  int*   slot     = (int*)(s_dst + N_NODES);                            // N
  int*   cursor   = slot + N_NODES;                                     // 8192
  float* scale_b  = (float*)(cursor + BATCH_N);                         // 8192
  int*   bucket_c = (int*)(scale_b + BATCH_N);                          // 8192*96 (3.1 MB)
  float* bucket_e = (float*)(bucket_c + (size_t)BATCH_N * BUCKET_CAP);  // 3.1 MB
  float* aggw     = bucket_e + (size_t)BATCH_N * BUCKET_CAP;            // 8192*256 (8 MB)

  prep_kernel<<<1, 256, 0, stream>>>(W, b, a, uv, consts);
  init_kernel<<<(N_NODES + 255) / 256, 256, 0, stream>>>(slot, cursor);
  slots_kernel<<<(BATCH_N + 255) / 256, 256, 0, stream>>>(batch_idx, slot);
  scores_kernel<<<(N_NODES * 64 + 255) / 256, 256, 0, stream>>>(feats, uv, consts, s_src, s_dst);
  scatter_kernel<<<(N_EDGES + 255) / 256, 256, 0, stream>>>(r, c, slot, s_src, s_dst,
                                                            cursor, bucket_c, bucket_e);
  agg_kernel<<<BATCH_N, 256, 0, stream>>>(feats, cursor, bucket_c, bucket_e, aggw, scale_b);
  gemm2_kernel<<<BATCH_N / 32, 256, 0, stream>>>(aggw, W, b, scale_b, out);
  fix_kernel<<<(BATCH_N * 64 + 255) / 256, 256, 0, stream>>>(batch_idx, slot, out);
}

// Round 7
// 228.299 us; speedup vs baseline: 2.8286x; 1.0737x over previous
//
#include <hip/hip_runtime.h>

#define N_NODES 100000
#define N_EDGES 1600000
#define IN_DIM  256
#define OUT_DIM 128
#define BATCH_N 8192
#define SLOPE   0.1f
#define EPS_V   1e-8f
#define BUCKET_CAP 96   // max fan-in per slot; Poisson(16) => P(>96) ~ 1e-40

// ---------------- setup: blocks 0..31 slot/cursor, block 32 prep ------------
// slot[] is NEVER initialized: scatter validates entries via back-pointer
// (batch_idx[sl]==rr), so garbage self-rejects. Duplicate-node races benign
// (one aligned-32b winner, all readers see it).
__global__ __launch_bounds__(256) void setup_kernel(const float* __restrict__ W,
                                                    const float* __restrict__ b,
                                                    const float* __restrict__ a,
                                                    const int* __restrict__ batch_idx,
                                                    int* __restrict__ slot,
                                                    int* __restrict__ cursor,
                                                    float* __restrict__ uv,       // [512]
                                                    float* __restrict__ consts) { // [2]
  const int blk = blockIdx.x, t = threadIdx.x;
  if (blk < 32) {
    int i = blk * 256 + t;                 // 32*256 == BATCH_N
    slot[batch_idx[i]] = i;
    cursor[i] = 0;
    return;
  }
  // block 32: uv[k] = (W@a1)[k], uv[256+k] = (W@a2)[k]; consts = {b.a1, b.a2}
  float su = 0.f, sv = 0.f;
  for (int j = 0; j < OUT_DIM; j++) {
    float w = W[t * OUT_DIM + j];
    su += w * a[j];
    sv += w * a[OUT_DIM + j];
  }
  uv[t] = su;
  uv[IN_DIM + t] = sv;

  __shared__ float red[256];
  float pb = (t < OUT_DIM) ? b[t] : 0.f;
  red[t] = (t < OUT_DIM) ? pb * a[t] : 0.f;
  __syncthreads();
  for (int off = 128; off > 0; off >>= 1) {
    if (t < off) red[t] += red[t + off];
    __syncthreads();
  }
  if (t == 0) consts[0] = red[0];
  __syncthreads();
  red[t] = (t < OUT_DIM) ? pb * a[OUT_DIM + t] : 0.f;
  __syncthreads();
  for (int off = 128; off > 0; off >>= 1) {
    if (t < off) red[t] += red[t + off];
    __syncthreads();
  }
  if (t == 0) consts[1] = red[0];
}

// ---------------- scores: one streaming pass over feats ---------------------
// s_src[i] = feats[i].u + cu ; s_dst[i] = feats[i].v + cv. Wave per node.
__global__ __launch_bounds__(256) void scores_kernel(const float* __restrict__ feats,
                                                     const float* __restrict__ uv,
                                                     const float* __restrict__ consts,
                                                     float* __restrict__ s_src,
                                                     float* __restrict__ s_dst) {
  int wid = (blockIdx.x * blockDim.x + threadIdx.x) >> 6;
  int lane = threadIdx.x & 63;
  if (wid >= N_NODES) return;
  float4 f  = *(const float4*)&feats[(size_t)wid * IN_DIM + lane * 4];
  float4 u4 = *(const float4*)&uv[lane * 4];
  float4 v4 = *(const float4*)&uv[IN_DIM + lane * 4];
  float p1 = f.x * u4.x + f.y * u4.y + f.z * u4.z + f.w * u4.w;
  float p2 = f.x * v4.x + f.y * v4.y + f.z * v4.z + f.w * v4.w;
#pragma unroll
  for (int s = 32; s > 0; s >>= 1) {
    p1 += __shfl_xor(p1, s);
    p2 += __shfl_xor(p2, s);
  }
  if (lane == 0) {
    s_src[wid] = p1 + consts[0];
    s_dst[wid] = p2 + consts[1];
  }
}

// ---------------- scatter: validated edges -> fixed-cap slot buckets --------
// Membership test is self-validating: slot[rr] is only trusted if the
// back-pointer batch_idx[sl] == rr. Works with uninitialized slot[].
__global__ __launch_bounds__(256) void scatter_kernel(const int* __restrict__ r, const int* __restrict__ c,
                                                      const int* __restrict__ slot,
                                                      const int* __restrict__ batch_idx,
                                                      const float* __restrict__ s_src,
                                                      const float* __restrict__ s_dst,
                                                      int* __restrict__ cursor,
                                                      int* __restrict__ bucket_c, float* __restrict__ bucket_e) {
  int i = blockIdx.x * blockDim.x + threadIdx.x;
  if (i >= N_EDGES) return;
  int rr = r[i];
  int sl = slot[rr];
  if (sl < 0 || sl >= BATCH_N) return;
  if (batch_idx[sl] != rr) return;       // garbage / non-batch self-rejects
  int cc = c[i];
  float x = s_src[rr] + s_dst[cc];
  float lr = x > 0.f ? x : SLOPE * x;
  float e = expf(lr);
  int pos = atomicAdd(&cursor[sl], 1);
  if (pos < BUCKET_CAP) {
    bucket_c[sl * BUCKET_CAP + pos] = cc;
    bucket_e[sl * BUCKET_CAP + pos] = e;
  }
}

// ---------------- agg: BLOCK (4 waves) per slot -----------------------------
// Buckets staged in LDS, edges split across waves, LDS combine, fused divide.
// aggw[sl] = (Sum e*feats[c])/(den+eps), scale_b[sl] = den/(den+eps).
// Loser duplicate slots have cursor==0 -> zeros (unused; gemm2 redirects).
__global__ __launch_bounds__(256) void agg_kernel(const float* __restrict__ feats,
                                                  const int* __restrict__ cursor,
                                                  const int* __restrict__ bucket_c,
                                                  const float* __restrict__ bucket_e,
                                                  float* __restrict__ aggw,
                                                  float* __restrict__ scale_b) {
  __shared__ int   sc[BUCKET_CAP];
  __shared__ float se[BUCKET_CAP];
  __shared__ float red[4][256];
  __shared__ float dred[4];
  const int sl = blockIdx.x;
  const int t = threadIdx.x, w = t >> 6, lane = t & 63;
  int cnt = cursor[sl];
  cnt = cnt > BUCKET_CAP ? BUCKET_CAP : cnt;
  if (t < cnt) {
    sc[t] = bucket_c[sl * BUCKET_CAP + t];
    se[t] = bucket_e[sl * BUCKET_CAP + t];
  }
  __syncthreads();
  float ax = 0.f, ay = 0.f, az = 0.f, aw = 0.f, den = 0.f;
#pragma unroll 2
  for (int j = w; j < cnt; j += 4) {
    int cc  = sc[j];
    float e = se[j];
    float4 f = *(const float4*)&feats[(size_t)cc * IN_DIM + lane * 4];
    ax += e * f.x; ay += e * f.y; az += e * f.z; aw += e * f.w;
    den += e;
  }
  *(float4*)&red[w][lane * 4] = make_float4(ax, ay, az, aw);
  if (lane == 0) dred[w] = den;
  __syncthreads();
  if (w == 0) {
    float4 r0 = *(float4*)&red[0][lane * 4];
    float4 r1 = *(float4*)&red[1][lane * 4];
    float4 r2 = *(float4*)&red[2][lane * 4];
    float4 r3 = *(float4*)&red[3][lane * 4];
    float d = dred[0] + dred[1] + dred[2] + dred[3];
    float dinv = 1.f / (d + EPS_V);
    *(float4*)&aggw[(size_t)sl * IN_DIM + lane * 4] =
        make_float4((r0.x + r1.x + r2.x + r3.x) * dinv,
                    (r0.y + r1.y + r2.y + r3.y) * dinv,
                    (r0.z + r1.z + r2.z + r3.z) * dinv,
                    (r0.w + r1.w + r2.w + r3.w) * dinv);
    if (lane == 0) scale_b[sl] = d * dinv;
  }
}

// ---------------- gemm2 (+fix fused): out[i] = aggw[win(i)]@W + sb*b --------
// win(i) = slot[batch_idx[i]] redirects duplicate batch rows to the winner's
// aggregate, eliminating the separate fix kernel.
// [8192 x 256] @ [256 x 128]; BM=32, BK=32, block=256 -> 256 blocks.
__global__ __launch_bounds__(256) void gemm2_kernel(const float* __restrict__ aggw,
                                                    const float* __restrict__ W,
                                                    const float* __restrict__ b,
                                                    const float* __restrict__ scale_b,
                                                    const int* __restrict__ batch_idx,
                                                    const int* __restrict__ slot,
                                                    float* __restrict__ out) {
  __shared__ float As[32][33];     // transposed [k][row]
  __shared__ float Ws[32][128];
  __shared__ int ridx[32];
  const int t = threadIdx.x;
  const int row0 = blockIdx.x * 32;
  const int tx = t & 31;           // cols tx*4 .. +3
  const int ty = t >> 5;           // rows ty*4 .. +3

  if (t < 32) ridx[t] = slot[batch_idx[row0 + t]];   // winner redirect
  __syncthreads();

  float acc[4][4];
#pragma unroll
  for (int i = 0; i < 4; i++)
#pragma unroll
    for (int j = 0; j < 4; j++) acc[i][j] = 0.f;

  for (int k0 = 0; k0 < IN_DIM; k0 += 32) {
    {
      int row = t >> 3, c4 = t & 7;   // 32 rows x 8 float4
      float4 v = *(const float4*)&aggw[(size_t)ridx[row] * IN_DIM + k0 + c4 * 4];
      As[c4 * 4 + 0][row] = v.x;
      As[c4 * 4 + 1][row] = v.y;
      As[c4 * 4 + 2][row] = v.z;
      As[c4 * 4 + 3][row] = v.w;
    }
#pragma unroll
    for (int p = 0; p < 4; p++) {
      int id = t + p * 256;
      int kr = id >> 5, c4 = id & 31;
      *(float4*)&Ws[kr][c4 * 4] = *(const float4*)&W[(size_t)(k0 + kr) * OUT_DIM + c4 * 4];
    }
    __syncthreads();
#pragma unroll
    for (int k = 0; k < 32; k++) {
      float av[4];
#pragma unroll
      for (int i = 0; i < 4; i++) av[i] = As[k][ty * 4 + i];
      float4 w4 = *(const float4*)&Ws[k][tx * 4];
#pragma unroll
      for (int i = 0; i < 4; i++) {
        acc[i][0] += av[i] * w4.x; acc[i][1] += av[i] * w4.y;
        acc[i][2] += av[i] * w4.z; acc[i][3] += av[i] * w4.w;
      }
    }
    __syncthreads();
  }
  float4 b4 = *(const float4*)&b[tx * 4];
#pragma unroll
  for (int i = 0; i < 4; i++) {
    int row = row0 + ty * 4 + i;
    float sb = scale_b[ridx[ty * 4 + i]];
    *(float4*)&out[(size_t)row * OUT_DIM + tx * 4] =
        make_float4(acc[i][0] + sb * b4.x, acc[i][1] + sb * b4.y,
                    acc[i][2] + sb * b4.z, acc[i][3] + sb * b4.w);
  }
}

extern "C" void kernel_launch(void* const* d_in, const int* in_sizes, int n_in,
                              void* d_out, int out_size, void* d_ws, size_t ws_size,
                              hipStream_t stream) {
  const float* feats     = (const float*)d_in[0];
  const float* W         = (const float*)d_in[1];
  const float* b         = (const float*)d_in[2];
  const float* a         = (const float*)d_in[3];
  const int*   r         = (const int*)d_in[4];
  const int*   c         = (const int*)d_in[5];
  const int*   batch_idx = (const int*)d_in[6];
  float* out = (float*)d_out;

  // workspace layout (~16 MB)
  float* uv       = (float*)d_ws;                                       // 512
  float* consts   = uv + 2 * IN_DIM;                                    // 8
  float* s_src    = consts + 8;                                         // N
  float* s_dst    = s_src + N_NODES;                                    // N
  int*   slot     = (int*)(s_dst + N_NODES);                            // N (uninitialized; validated)
  int*   cursor   = slot + N_NODES;                                     // 8192
  float* scale_b  = (float*)(cursor + BATCH_N);                         // 8192
  int*   bucket_c = (int*)(scale_b + BATCH_N);                          // 8192*96 (3.1 MB)
  float* bucket_e = (float*)(bucket_c + (size_t)BATCH_N * BUCKET_CAP);  // 3.1 MB
  float* aggw     = bucket_e + (size_t)BATCH_N * BUCKET_CAP;            // 8192*256 (8 MB)

  setup_kernel<<<33, 256, 0, stream>>>(W, b, a, batch_idx, slot, cursor, uv, consts);
  scores_kernel<<<(N_NODES * 64 + 255) / 256, 256, 0, stream>>>(feats, uv, consts, s_src, s_dst);
  scatter_kernel<<<(N_EDGES + 255) / 256, 256, 0, stream>>>(r, c, slot, batch_idx, s_src, s_dst,
                                                            cursor, bucket_c, bucket_e);
  agg_kernel<<<BATCH_N, 256, 0, stream>>>(feats, cursor, bucket_c, bucket_e, aggw, scale_b);
  gemm2_kernel<<<BATCH_N / 32, 256, 0, stream>>>(aggw, W, b, scale_b, batch_idx, slot, out);
}

// Round 10
// 215.772 us; speedup vs baseline: 2.9928x; 1.0581x over previous
//
#include <hip/hip_runtime.h>

#define N_NODES 100000
#define N_EDGES 1600000
#define IN_DIM  256
#define OUT_DIM 128
#define BATCH_N 8192
#define SLOPE   0.1f
#define EPS_V   1e-8f
#define BUCKET_CAP 96   // max fan-in per slot; Poisson(16) => P(>96) ~ 1e-40

// ---------------- setup: blocks 0..31 slot/cursor, block 32 prep ------------
// slot[] is NEVER initialized: scatter validates entries via back-pointer
// (batch_idx[sl]==rr), so garbage self-rejects. Duplicate-node races benign
// (one aligned-32b winner, all readers see it).
__global__ __launch_bounds__(256) void setup_kernel(const float* __restrict__ W,
                                                    const float* __restrict__ b,
                                                    const float* __restrict__ a,
                                                    const int* __restrict__ batch_idx,
                                                    int* __restrict__ slot,
                                                    int* __restrict__ cursor,
                                                    float* __restrict__ uv,       // [512]
                                                    float* __restrict__ consts) { // [2]
  const int blk = blockIdx.x, t = threadIdx.x;
  if (blk < 32) {
    int i = blk * 256 + t;                 // 32*256 == BATCH_N
    slot[batch_idx[i]] = i;
    cursor[i] = 0;
    return;
  }
  // block 32: uv[k] = (W@a1)[k], uv[256+k] = (W@a2)[k]; consts = {b.a1, b.a2}
  float su = 0.f, sv = 0.f;
  for (int j = 0; j < OUT_DIM; j++) {
    float w = W[t * OUT_DIM + j];
    su += w * a[j];
    sv += w * a[OUT_DIM + j];
  }
  uv[t] = su;
  uv[IN_DIM + t] = sv;

  __shared__ float red[256];
  float pb = (t < OUT_DIM) ? b[t] : 0.f;
  red[t] = (t < OUT_DIM) ? pb * a[t] : 0.f;
  __syncthreads();
  for (int off = 128; off > 0; off >>= 1) {
    if (t < off) red[t] += red[t + off];
    __syncthreads();
  }
  if (t == 0) consts[0] = red[0];
  __syncthreads();
  red[t] = (t < OUT_DIM) ? pb * a[OUT_DIM + t] : 0.f;
  __syncthreads();
  for (int off = 128; off > 0; off >>= 1) {
    if (t < off) red[t] += red[t + off];
    __syncthreads();
  }
  if (t == 0) consts[1] = red[0];
}

// ---------------- scatter: validated edges -> slot buckets (indices only) ---
// No score math here: e is computed in agg from the feats row it gathers
// anyway. c[] is read only for accepted (~8%) edges.
__global__ __launch_bounds__(256) void scatter_kernel(const int* __restrict__ r, const int* __restrict__ c,
                                                      const int* __restrict__ slot,
                                                      const int* __restrict__ batch_idx,
                                                      int* __restrict__ cursor,
                                                      int* __restrict__ bucket_c) {
  int i = blockIdx.x * blockDim.x + threadIdx.x;
  if (i >= N_EDGES) return;
  int rr = r[i];
  int sl = slot[rr];
  if ((unsigned)sl >= (unsigned)BATCH_N) return;
  if (batch_idx[sl] != rr) return;       // garbage / non-batch self-rejects
  int pos = atomicAdd(&cursor[sl], 1);
  if (pos < BUCKET_CAP) bucket_c[sl * BUCKET_CAP + pos] = c[i];
}

// ---------------- agg: BLOCK (4 waves) per slot; score fused ----------------
// Per entry: gather feats[cc] (needed for the sum anyway), s_dst on the fly
// = dot(f, v)+cv via shfl reduce, e = exp(leaky(s_src_sl + s_dst)),
// accumulate e*f. s_src_sl from one extra row gather (feats[batch_idx[sl]]).
// aggw[sl] = (Sum e*f)/(den+eps), scale_b[sl] = den/(den+eps).
__global__ __launch_bounds__(256) void agg_kernel(const float* __restrict__ feats,
                                                  const int* __restrict__ cursor,
                                                  const int* __restrict__ bucket_c,
                                                  const int* __restrict__ batch_idx,
                                                  const float* __restrict__ uv,
                                                  const float* __restrict__ consts,
                                                  float* __restrict__ aggw,
                                                  float* __restrict__ scale_b) {
  __shared__ int   sc[BUCKET_CAP];
  __shared__ float red[4][256];
  __shared__ float dred[4];
  const int sl = blockIdx.x;
  const int t = threadIdx.x, w = t >> 6, lane = t & 63;
  int cnt = cursor[sl];
  cnt = cnt > BUCKET_CAP ? BUCKET_CAP : cnt;
  if (t < cnt) sc[t] = bucket_c[sl * BUCKET_CAP + t];

  float4 u4 = *(const float4*)&uv[lane * 4];
  float4 v4 = *(const float4*)&uv[IN_DIM + lane * 4];
  // s_src for this slot's node (each wave computes it redundantly — cheap)
  int node = batch_idx[sl];
  float4 fr = *(const float4*)&feats[(size_t)node * IN_DIM + lane * 4];
  float p1 = fr.x * u4.x + fr.y * u4.y + fr.z * u4.z + fr.w * u4.w;
#pragma unroll
  for (int s2 = 32; s2 > 0; s2 >>= 1) p1 += __shfl_xor(p1, s2);
  const float ssrc = p1 + consts[0];
  const float cv = consts[1];
  __syncthreads();

  float ax = 0.f, ay = 0.f, az = 0.f, aw = 0.f, den = 0.f;
#pragma unroll 2
  for (int j = w; j < cnt; j += 4) {
    int cc = sc[j];
    float4 f = *(const float4*)&feats[(size_t)cc * IN_DIM + lane * 4];
    float p2 = f.x * v4.x + f.y * v4.y + f.z * v4.z + f.w * v4.w;
#pragma unroll
    for (int s2 = 32; s2 > 0; s2 >>= 1) p2 += __shfl_xor(p2, s2);
    float x = ssrc + p2 + cv;
    float lr = x > 0.f ? x : SLOPE * x;
    float e = expf(lr);
    ax += e * f.x; ay += e * f.y; az += e * f.z; aw += e * f.w;
    den += e;
  }
  *(float4*)&red[w][lane * 4] = make_float4(ax, ay, az, aw);
  if (lane == 0) dred[w] = den;
  __syncthreads();
  if (w == 0) {
    float4 r0 = *(float4*)&red[0][lane * 4];
    float4 r1 = *(float4*)&red[1][lane * 4];
    float4 r2 = *(float4*)&red[2][lane * 4];
    float4 r3 = *(float4*)&red[3][lane * 4];
    float d = dred[0] + dred[1] + dred[2] + dred[3];
    float dinv = 1.f / (d + EPS_V);
    *(float4*)&aggw[(size_t)sl * IN_DIM + lane * 4] =
        make_float4((r0.x + r1.x + r2.x + r3.x) * dinv,
                    (r0.y + r1.y + r2.y + r3.y) * dinv,
                    (r0.z + r1.z + r2.z + r3.z) * dinv,
                    (r0.w + r1.w + r2.w + r3.w) * dinv);
    if (lane == 0) scale_b[sl] = d * dinv;
  }
}

// ---------------- gemm2 (+fix fused): out[i] = aggw[win(i)]@W + sb*b --------
// win(i) = slot[batch_idx[i]] redirects duplicate batch rows to the winner's
// aggregate. [8192 x 256] @ [256 x 128]; BM=32, BK=32, block=256.
__global__ __launch_bounds__(256) void gemm2_kernel(const float* __restrict__ aggw,
                                                    const float* __restrict__ W,
                                                    const float* __restrict__ b,
                                                    const float* __restrict__ scale_b,
                                                    const int* __restrict__ batch_idx,
                                                    const int* __restrict__ slot,
                                                    float* __restrict__ out) {
  __shared__ float As[32][33];     // transposed [k][row]
  __shared__ float Ws[32][128];
  __shared__ int ridx[32];
  const int t = threadIdx.x;
  const int row0 = blockIdx.x * 32;
  const int tx = t & 31;           // cols tx*4 .. +3
  const int ty = t >> 5;           // rows ty*4 .. +3

  if (t < 32) ridx[t] = slot[batch_idx[row0 + t]];   // winner redirect
  __syncthreads();

  float acc[4][4];
#pragma unroll
  for (int i = 0; i < 4; i++)
#pragma unroll
    for (int j = 0; j < 4; j++) acc[i][j] = 0.f;

  for (int k0 = 0; k0 < IN_DIM; k0 += 32) {
    {
      int row = t >> 3, c4 = t & 7;   // 32 rows x 8 float4
      float4 v = *(const float4*)&aggw[(size_t)ridx[row] * IN_DIM + k0 + c4 * 4];
      As[c4 * 4 + 0][row] = v.x;
      As[c4 * 4 + 1][row] = v.y;
      As[c4 * 4 + 2][row] = v.z;
      As[c4 * 4 + 3][row] = v.w;
    }
#pragma unroll
    for (int p = 0; p < 4; p++) {
      int id = t + p * 256;
      int kr = id >> 5, c4 = id & 31;
      *(float4*)&Ws[kr][c4 * 4] = *(const float4*)&W[(size_t)(k0 + kr) * OUT_DIM + c4 * 4];
    }
    __syncthreads();
#pragma unroll
    for (int k = 0; k < 32; k++) {
      float av[4];
#pragma unroll
      for (int i = 0; i < 4; i++) av[i] = As[k][ty * 4 + i];
      float4 w4 = *(const float4*)&Ws[k][tx * 4];
#pragma unroll
      for (int i = 0; i < 4; i++) {
        acc[i][0] += av[i] * w4.x; acc[i][1] += av[i] * w4.y;
        acc[i][2] += av[i] * w4.z; acc[i][3] += av[i] * w4.w;
      }
    }
    __syncthreads();
  }
  float4 b4 = *(const float4*)&b[tx * 4];
#pragma unroll
  for (int i = 0; i < 4; i++) {
    int row = row0 + ty * 4 + i;
    float sb = scale_b[ridx[ty * 4 + i]];
    *(float4*)&out[(size_t)row * OUT_DIM + tx * 4] =
        make_float4(acc[i][0] + sb * b4.x, acc[i][1] + sb * b4.y,
                    acc[i][2] + sb * b4.z, acc[i][3] + sb * b4.w);
  }
}

extern "C" void kernel_launch(void* const* d_in, const int* in_sizes, int n_in,
                              void* d_out, int out_size, void* d_ws, size_t ws_size,
                              hipStream_t stream) {
  const float* feats     = (const float*)d_in[0];
  const float* W         = (const float*)d_in[1];
  const float* b         = (const float*)d_in[2];
  const float* a         = (const float*)d_in[3];
  const int*   r         = (const int*)d_in[4];
  const int*   c         = (const int*)d_in[5];
  const int*   batch_idx = (const int*)d_in[6];
  float* out = (float*)d_out;

  // workspace layout (~12.5 MB)
  float* uv       = (float*)d_ws;                                       // 512
  float* consts   = uv + 2 * IN_DIM;                                    // 8
  int*   slot     = (int*)(consts + 8);                                 // N (uninitialized; validated)
  int*   cursor   = slot + N_NODES;                                     // 8192
  float* scale_b  = (float*)(cursor + BATCH_N);                         // 8192
  int*   bucket_c = (int*)(scale_b + BATCH_N);                          // 8192*96 (3.1 MB)
  float* aggw     = (float*)(bucket_c + (size_t)BATCH_N * BUCKET_CAP);  // 8192*256 (8 MB)

  setup_kernel<<<33, 256, 0, stream>>>(W, b, a, batch_idx, slot, cursor, uv, consts);
  scatter_kernel<<<(N_EDGES + 255) / 256, 256, 0, stream>>>(r, c, slot, batch_idx,
                                                            cursor, bucket_c);
  agg_kernel<<<BATCH_N, 256, 0, stream>>>(feats, cursor, bucket_c, batch_idx, uv, consts,
                                          aggw, scale_b);
  gemm2_kernel<<<BATCH_N / 32, 256, 0, stream>>>(aggw, W, b, scale_b, batch_idx, slot, out);
}